// Round 6
// baseline (226.974 us; speedup 1.0000x reference)
//
#include <hip/hip_runtime.h>
#include <math.h>

#define B_SZ   64
#define T_SZ   512
#define DOBS   128
#define DLAT   16
#define DHID   256
#define K_SZ   8
#define ROWS_A 32768   // B*T

#define LOG2PI_F 1.8378770664093453f
#define VAR_F    5.0e-4f

// ws float offsets
#define LINV0_OFF   16
#define LOGDET0_OFF 2064
#define LINVT_OFF   2080
#define LOGDETT_OFF 4128
#define CVEC_OFF    4224      // 8*16 floats: Linv_k @ bt2_k
// ws[0]=recon_sum ws[1]=logq_sum ws[2]=msm_sum ws[5]=hmm ticket
#define WIMG_F_OFF  8192      // bf16 weight images start here (ushort region)
#define EVT_WS_OFF  131072    // evT staging: 262144 floats in ws (NOT in d_out)

// bf16 weight image offsets (in shorts, within wimg)
#define EVT_W1   0            // [k][ch=256][d pad24]  d<16: Wt1, d==16: bt1, d>16: 0
#define EVT_W2   49152        // [k][d2=16][kk pad264] <- (Wt2@LinvT)[k][ch][d2], kk=perm(ch)
#define EVT_LINV 82944        // [k][i=16][j pad24]    <- LinvT[k][i][j]
#define ENC_W1   86016        // [n=256][kk=128 pad136] <- W1[kk][n]
#define ENC_W2   120832       // [n=32][kk=256 pad264]  <- W2[kk][n], kk=perm
#define DEC_W1   129280       // [n=256][d pad24]  d<16: Wd1, d==16: bd1, d>16: 0
#define DEC_W2   135424       // [n=128][kk=256 pad264] <- Wd2[kk][n], kk=perm
#define WCVT_TOTAL 182272     // grid-stride element count (incl. pad slots)

#define Z_OUT_OFF   4194304   // B*T*DOBS
#define LOSS_OFF    4718592   // + B*T*DLAT
#define PBUF_OFF  262144      // W2L f32 staging between prep and wcvt (in d_out)

typedef __attribute__((ext_vector_type(8))) short short8;
typedef __attribute__((ext_vector_type(8))) unsigned short ush8;
typedef __attribute__((ext_vector_type(4))) float floatx4;

__device__ __forceinline__ float leakyf(float v) { return v > 0.f ? v : 0.01f * v; }
__device__ __forceinline__ unsigned short f2bf(float f) {
  union { float f; unsigned int u; } v; v.f = f;
  unsigned int lsb = (v.u >> 16) & 1;
  v.u += 0x7fffu + lsb;   // round-to-nearest-even
  return (unsigned short)(v.u >> 16);
}
// packed f32x2 -> bf16x2 (RNE), single VALU op on gfx950
__device__ __forceinline__ unsigned int cvt_pk_bf16(float lo, float hi) {
  unsigned int r;
  asm("v_cvt_pk_bf16_f32 %0, %1, %2" : "=v"(r) : "v"(lo), "v"(hi));
  return r;
}
// softplus via native ocml intrinsics (no denorm guards). |v| <~ 4 here.
__device__ __forceinline__ float softplus_fast(float v) {
  return __logf(1.f + __expf(v));
}
// kk-permutation pairing even/odd channels for b32 ttile writes
__device__ __forceinline__ int permk(int kk) {
  return (kk & ~31) | ((kk & 15) << 1) | ((kk >> 4) & 1);
}

// ---------------------------------------------------------------------------
// prep: per-k Cholesky of C C^T + 1e-6 I, then Linv, logdet.
// Jobs 8..15 additionally compute W2L = Wt2@LinvT (f32, to out+PBUF staging)
// and cvec = Linv@bt2 (to ws). Job 0 zeroes the ws accumulators + tickets.
// ---------------------------------------------------------------------------
__global__ __launch_bounds__(256) void prep_kernel(const float* __restrict__ init_cov,
                                                   const float* __restrict__ covs,
                                                   const float* __restrict__ Wt2,
                                                   const float* __restrict__ bt2,
                                                   float* __restrict__ ws,
                                                   float* __restrict__ w2l) {
  __shared__ float M[16][16];
  __shared__ float L[16][16];
  __shared__ float X[16][17];
  int job = blockIdx.x;
  const float* C = (job < 8) ? (init_cov + job * 256) : (covs + (job - 8) * 256);
  float* linv = ws + ((job < 8) ? (LINV0_OFF + job * 256) : (LINVT_OFF + (job - 8) * 256));
  float* logdet = ws + ((job < 8) ? (LOGDET0_OFF + job) : (LOGDETT_OFF + (job - 8)));
  int tid = threadIdx.x;
  if (job == 0 && tid < 8) ws[tid] = 0.f;
  int i = tid >> 4, j = tid & 15;
  {
    float s = (i == j) ? 1e-6f : 0.f;
    #pragma unroll
    for (int p = 0; p < 16; ++p) s += C[i * 16 + p] * C[j * 16 + p];
    M[i][j] = s;
  }
  __syncthreads();
  for (int c = 0; c < 16; ++c) {
    if (tid == 0) {
      float s = M[c][c];
      for (int p = 0; p < c; ++p) s -= L[c][p] * L[c][p];
      L[c][c] = sqrtf(s);
    }
    __syncthreads();
    if (tid > c && tid < 16) {
      float s = M[tid][c];
      for (int p = 0; p < c; ++p) s -= L[tid][p] * L[c][p];
      L[tid][c] = s / L[c][c];
    }
    __syncthreads();
  }
  if (tid < 16) {
    for (int r = 0; r < 16; ++r) {
      float s = (r == tid) ? 1.f : 0.f;
      for (int p = tid; p < r; ++p) s -= L[r][p] * X[p][tid];
      X[r][tid] = (r >= tid) ? s / L[r][r] : 0.f;
    }
  }
  __syncthreads();
  linv[i * 16 + j] = X[i][j];
  if (tid == 0) {
    float s = 0.f;
    for (int d = 0; d < 16; ++d) s += logf(L[d][d]);
    *logdet = 2.f * s;
  }
  if (job >= 8) {
    int k = job - 8;
    // W2L[k][h][i] = sum_j Wt2[k][h][j] * Linv[i][j]   (X lower-tri)
    const float* wrow = Wt2 + (long)k * 4096 + tid * 16;
    float* orow = w2l + (long)k * 4096 + tid * 16;
    #pragma unroll
    for (int i2 = 0; i2 < 16; ++i2) {
      float s = 0.f;
      for (int jj = 0; jj <= i2; ++jj) s += wrow[jj] * X[i2][jj];
      orow[i2] = s;
    }
    if (tid < 16) {
      float s = 0.f;
      const float* b = bt2 + k * 16;
      for (int jj = 0; jj <= tid; ++jj) s += b[jj] * X[tid][jj];
      ws[CVEC_OFF + k * 16 + tid] = s;
    }
  }
}

// ---------------------------------------------------------------------------
// wcvt: one-time fp32 -> bf16 weight-image conversion (frag-ready layouts).
// ---------------------------------------------------------------------------
__global__ __launch_bounds__(256) void wcvt_kernel(
    const float* __restrict__ Wt1, const float* __restrict__ bt1,
    const float* __restrict__ W1, const float* __restrict__ W2,
    const float* __restrict__ Wd1, const float* __restrict__ bd1,
    const float* __restrict__ Wd2,
    const float* __restrict__ ws, const float* __restrict__ w2l,
    unsigned short* __restrict__ wimg) {
  for (int e = blockIdx.x * 256 + threadIdx.x; e < WCVT_TOTAL; e += gridDim.x * 256) {
    if (e < 65536) {                       // EVT_W1 + bias row (d=16) + zeros
      int k = e >> 13, r = e & 8191, ch = r >> 5, d = r & 31;
      if (d < 24) {
        float v = (d < 16) ? Wt1[k * 4096 + d * 256 + ch]
                           : ((d == 16) ? bt1[k * 256 + ch] : 0.f);
        wimg[EVT_W1 + k * 6144 + ch * 24 + d] = f2bf(v);
      }
    } else if (e < 98304) {                // EVT_W2 from W2L, kk permuted
      int e2 = e - 65536; int k = e2 >> 12, r = e2 & 4095, d2 = r >> 8, h = r & 255;
      wimg[EVT_W2 + k * 4224 + d2 * 264 + permk(h)] = f2bf(w2l[(long)k * 4096 + h * 16 + d2]);
    } else if (e < 100352) {               // EVT_LINV
      int e2 = e - 98304; int k = e2 >> 8, r = e2 & 255, i = r >> 4, j = r & 15;
      wimg[EVT_LINV + k * 384 + i * 24 + j] = f2bf(ws[LINVT_OFF + k * 256 + i * 16 + j]);
    } else if (e < 133120) {               // ENC_W1
      int e2 = e - 100352; int n = e2 >> 7, kk = e2 & 127;
      wimg[ENC_W1 + n * 136 + kk] = f2bf(W1[kk * 256 + n]);
    } else if (e < 141312) {               // ENC_W2, kk permuted
      int e2 = e - 133120; int n = e2 >> 8, kk = e2 & 255;
      wimg[ENC_W2 + n * 264 + permk(kk)] = f2bf(W2[kk * 32 + n]);
    } else if (e < 149504) {               // DEC_W1 + bias row
      int e2 = e - 141312; int n = e2 >> 5, d = e2 & 31;
      if (d < 24) {
        float v = (d < 16) ? Wd1[d * 256 + n] : ((d == 16) ? bd1[n] : 0.f);
        wimg[DEC_W1 + n * 24 + d] = f2bf(v);
      }
    } else {                               // DEC_W2, kk permuted
      int e2 = e - 149504; int kk = e2 >> 7, n = e2 & 127;
      wimg[DEC_W2 + n * 264 + permk(kk)] = f2bf(Wd2[kk * 128 + n]);
    }
  }
}

// ---------------------------------------------------------------------------
// encoder (bf16 MFMA, interleaved): per 16-row tile,
// GEMM1 col-pair -> leaky -> paired b32 LDS transpose tile -> GEMM2.
// ---------------------------------------------------------------------------
__global__ __launch_bounds__(256) void enc_kernel(
    const float* __restrict__ x, const float* __restrict__ eps,
    const float* __restrict__ b1, const float* __restrict__ b2,
    const unsigned short* __restrict__ wimg,
    float* __restrict__ z_out, float* __restrict__ ws) {
  __shared__ __align__(16) unsigned short w2t[32 * 264];
  __shared__ __align__(16) unsigned short ttile[4][16 * 56];
  __shared__ float b1s[256];
  __shared__ float sred;
  int tid = threadIdx.x;
  if (tid == 0) sred = 0.f;
  {
    const ush8* s2 = (const ush8*)(wimg + ENC_W2);
    for (int e = tid; e < 1056; e += 256) ((ush8*)w2t)[e] = s2[e];
    b1s[tid] = b1[tid];
  }
  __syncthreads();

  int wid = tid >> 6, lane = tid & 63;
  int m = lane & 15, quad = lane >> 4;
  unsigned short* tt = ttile[wid];
  const unsigned short* w1i = wimg + ENC_W1;
  long rowb = (long)blockIdx.x * 64 + wid * 16;

  short8 xa[4];
  const float* xp = x + (rowb + m) * 128 + quad * 8;
  #pragma unroll
  for (int kt = 0; kt < 4; ++kt) {
    float4 f0 = *(const float4*)(xp + kt * 32);
    float4 f1 = *(const float4*)(xp + kt * 32 + 4);
    union { unsigned int u[4]; short8 s; } cv;
    cv.u[0] = cvt_pk_bf16(f0.x, f0.y);
    cv.u[1] = cvt_pk_bf16(f0.z, f0.w);
    cv.u[2] = cvt_pk_bf16(f1.x, f1.y);
    cv.u[3] = cvt_pk_bf16(f1.z, f1.w);
    xa[kt] = cv.s;
  }
  float bm0 = b2[m], bm1 = b2[16 + m];
  floatx4 a20 = {bm0, bm0, bm0, bm0};
  floatx4 a21 = {bm1, bm1, bm1, bm1};
  #pragma unroll
  for (int cp = 0; cp < 8; ++cp) {
    floatx4 a1h[2];
    #pragma unroll
    for (int h = 0; h < 2; ++h) {
      int c = cp * 2 + h;
      float bias = b1s[c * 16 + m];
      floatx4 a1 = {bias, bias, bias, bias};
      #pragma unroll
      for (int kt = 0; kt < 4; ++kt) {
        short8 bf = *(const short8*)&w1i[(c * 16 + m) * 136 + kt * 32 + quad * 8];
        a1 = __builtin_amdgcn_mfma_f32_16x16x32_bf16(xa[kt], bf, a1, 0, 0, 0);
      }
      a1h[h] = a1;
    }
    #pragma unroll
    for (int g = 0; g < 4; ++g) {
      unsigned int p = cvt_pk_bf16(leakyf(a1h[0][g]), leakyf(a1h[1][g]));
      *(unsigned int*)&tt[(quad * 4 + g) * 56 + 2 * m] = p;
    }
    short8 ha = *(const short8*)&tt[m * 56 + quad * 8];
    short8 wb0 = *(const short8*)&w2t[m * 264 + cp * 32 + quad * 8];
    short8 wb1 = *(const short8*)&w2t[(16 + m) * 264 + cp * 32 + quad * 8];
    a20 = __builtin_amdgcn_mfma_f32_16x16x32_bf16(ha, wb0, a20, 0, 0, 0);
    a21 = __builtin_amdgcn_mfma_f32_16x16x32_bf16(ha, wb1, a21, 0, 0, 0);
  }
  // epilogue: z + logq
  float logq_acc = 0.f;
  #pragma unroll
  for (int g = 0; g < 4; ++g) {
    long row = rowb + quad * 4 + g;
    float mu = a20[g], lv = a21[g];
    float ev = eps[row * 16 + m];
    float zv = mu + __expf(0.5f * lv) * ev;
    z_out[row * 16 + m] = zv;
    float zz = zv - mu;
    logq_acc += lv + zz * zz * __expf(-lv);
  }
  #pragma unroll
  for (int off = 1; off < 64; off <<= 1) logq_acc += __shfl_xor(logq_acc, off, 64);
  if (lane == 0) atomicAdd(&sred, -0.5f * logq_acc);
  __syncthreads();
  if (tid == 0) atomicAdd(&ws[1], sred - 0.5f * 16.f * LOG2PI_F * 64.f);
}

// ---------------------------------------------------------------------------
// evtdec v2 (occupancy diet): dec reads DEC_W1 from global (L2-hot) instead
// of LDS, shrinking wbuf to evt's 4608 ushorts. LDS ~17 KB -> 8 blocks/CU.
// ---------------------------------------------------------------------------
__global__ __launch_bounds__(256, 8) void evtdec_kernel(
    const float* __restrict__ x, const float* __restrict__ z,
    const float* __restrict__ bd2,
    const unsigned short* __restrict__ wimg,
    float* __restrict__ evT, float* __restrict__ xhat,
    float* __restrict__ ws) {
  __shared__ __align__(16) unsigned short wbuf[4608];     // evt: w2t(4224)+linvb(384)
  __shared__ __align__(16) unsigned short ttile[4][16 * 56];
  __shared__ float fbuf[132];                              // dec: bd2s[128], fbuf[128]=sred
  int tid = threadIdx.x;
  int wid = tid >> 6, lane = tid & 63;
  int m = lane & 15, quad = lane >> 4;
  unsigned short* tt = ttile[wid];

  if (blockIdx.x < 256) {
    // ================= evt path =================
    int k = blockIdx.y;
    {
      const ush8* s2 = (const ush8*)(wimg + EVT_W2 + k * 4224);
      for (int e = tid; e < 528; e += 256) ((ush8*)wbuf)[e] = s2[e];
      if (tid < 48) ((ush8*)(wbuf + 4224))[tid] = ((const ush8*)(wimg + EVT_LINV + k * 384))[tid];
    }
    float logdetk = ws[LOGDETT_OFF + k];
    __syncthreads();
    const unsigned short* w2t = wbuf;
    const unsigned short* linvb = wbuf + 4224;
    const unsigned short* w1i = wimg + EVT_W1 + k * 6144;
    float cval = ws[CVEC_OFF + k * 16 + m];

    for (int tile = 0; tile < 2; ++tile) {
      long rowb = (long)blockIdx.x * 128 + wid * 32 + tile * 16;
      short8 za = (short8)0;
      if (quad < 2) {
        const float* zp = z + (rowb + m) * 16 + quad * 8;
        float4 f0 = *(const float4*)zp;
        float4 f1 = *(const float4*)(zp + 4);
        union { unsigned int u[4]; short8 s; } cv;
        cv.u[0] = cvt_pk_bf16(f0.x, f0.y);
        cv.u[1] = cvt_pk_bf16(f0.z, f0.w);
        cv.u[2] = cvt_pk_bf16(f1.x, f1.y);
        cv.u[3] = cvt_pk_bf16(f1.z, f1.w);
        za = cv.s;
      } else if (quad == 2) {
        za[0] = (short)0x3F80;   // bf16(1.0) -> picks up bias row d=16
      }
      short8 za2 = (short8)0;
      if (quad < 2) {
        long r2 = rowb + m + 1; if (r2 > 32767) r2 = 32767;
        const float* zp2 = z + r2 * 16 + quad * 8;
        float4 f0 = *(const float4*)zp2;
        float4 f1 = *(const float4*)(zp2 + 4);
        union { unsigned int u[4]; short8 s; } cv;
        cv.u[0] = cvt_pk_bf16(f0.x, f0.y);
        cv.u[1] = cvt_pk_bf16(f0.z, f0.w);
        cv.u[2] = cvt_pk_bf16(f1.x, f1.y);
        cv.u[3] = cvt_pk_bf16(f1.z, f1.w);
        za2 = cv.s;
      }
      floatx4 a2 = {cval, cval, cval, cval};   // cvec + ht@W2L accumulates here
      #pragma unroll
      for (int cp = 0; cp < 8; ++cp) {
        floatx4 a1h[2];
        #pragma unroll
        for (int h = 0; h < 2; ++h) {
          int c = cp * 2 + h;
          short8 bfrag = (short8)0;
          if (quad < 3) bfrag = *(const short8*)&w1i[(c * 16 + m) * 24 + quad * 8];
          floatx4 a1 = {0.f, 0.f, 0.f, 0.f};
          a1 = __builtin_amdgcn_mfma_f32_16x16x32_bf16(za, bfrag, a1, 0, 0, 0);
          a1h[h] = a1;
        }
        #pragma unroll
        for (int g = 0; g < 4; ++g) {
          unsigned int p = cvt_pk_bf16(softplus_fast(a1h[0][g]), softplus_fast(a1h[1][g]));
          *(unsigned int*)&tt[(quad * 4 + g) * 56 + 2 * m] = p;
        }
        short8 ha = *(const short8*)&tt[m * 56 + quad * 8];
        short8 wb = *(const short8*)&w2t[m * 264 + cp * 32 + quad * 8];
        a2 = __builtin_amdgcn_mfma_f32_16x16x32_bf16(ha, wb, a2, 0, 0, 0);
      }
      short8 lb = (short8)0;
      if (quad < 2) lb = *(const short8*)&linvb[m * 24 + quad * 8];
      floatx4 a3 = {0.f, 0.f, 0.f, 0.f};
      a3 = __builtin_amdgcn_mfma_f32_16x16x32_bf16(za2, lb, a3, 0, 0, 0);
      #pragma unroll
      for (int g = 0; g < 4; ++g) {
        float v = a3[g] - a2[g];
        v = v * v;
        v += __shfl_xor(v, 1, 64);
        v += __shfl_xor(v, 2, 64);
        v += __shfl_xor(v, 4, 64);
        v += __shfl_xor(v, 8, 64);
        long grow = rowb + quad * 4 + g;
        if (m == 0 && (grow & 511) != 511) {
          long r1 = grow + 1;
          evT[(r1 >> 9) * 4096 + (long)k * 512 + (r1 & 511)] =
              -0.5f * (16.f * LOG2PI_F + logdetk + v);
        }
      }
    }
  } else {
    // ================= dec path (w1 from global image, L2-hot) =============
    int decb = blockIdx.y * 64 + ((int)blockIdx.x - 256);
    if (tid == 0) fbuf[128] = 0.f;
    if (tid < 128) fbuf[tid] = bd2[tid];
    __syncthreads();
    const unsigned short* w1i = wimg + DEC_W1;
    const unsigned short* w2i = wimg + DEC_W2;
    long rowb = (long)decb * 64 + wid * 16;

    short8 za = (short8)0;
    if (quad < 2) {
      const float* zp = z + (rowb + m) * 16 + quad * 8;
      float4 f0 = *(const float4*)zp;
      float4 f1 = *(const float4*)(zp + 4);
      union { unsigned int u[4]; short8 s; } cv;
      cv.u[0] = cvt_pk_bf16(f0.x, f0.y);
      cv.u[1] = cvt_pk_bf16(f0.z, f0.w);
      cv.u[2] = cvt_pk_bf16(f1.x, f1.y);
      cv.u[3] = cvt_pk_bf16(f1.z, f1.w);
      za = cv.s;
    } else if (quad == 2) {
      za[0] = (short)0x3F80;   // bias row pickup
    }
    floatx4 a2[8];
    #pragma unroll
    for (int c2 = 0; c2 < 8; ++c2) {
      float bv = fbuf[c2 * 16 + m];
      a2[c2] = (floatx4){bv, bv, bv, bv};
    }
    #pragma unroll
    for (int cp = 0; cp < 8; ++cp) {
      floatx4 a1h[2];
      #pragma unroll
      for (int h = 0; h < 2; ++h) {
        int c = cp * 2 + h;
        short8 bfrag = (short8)0;
        if (quad < 3) bfrag = *(const short8*)&w1i[(c * 16 + m) * 24 + quad * 8];
        floatx4 a1 = {0.f, 0.f, 0.f, 0.f};
        a1 = __builtin_amdgcn_mfma_f32_16x16x32_bf16(za, bfrag, a1, 0, 0, 0);
        a1h[h] = a1;
      }
      #pragma unroll
      for (int g = 0; g < 4; ++g) {
        unsigned int p = cvt_pk_bf16(leakyf(a1h[0][g]), leakyf(a1h[1][g]));
        *(unsigned int*)&tt[(quad * 4 + g) * 56 + 2 * m] = p;
      }
      short8 ha = *(const short8*)&tt[m * 56 + quad * 8];
      #pragma unroll
      for (int c2 = 0; c2 < 8; ++c2) {
        short8 wb = *(const short8*)&w2i[(c2 * 16 + m) * 264 + cp * 32 + quad * 8];
        a2[c2] = __builtin_amdgcn_mfma_f32_16x16x32_bf16(ha, wb, a2[c2], 0, 0, 0);
      }
    }
    const float C0 = -0.5f * logf(6.2831853071795864f * VAR_F);
    float rsum = 0.f;
    #pragma unroll
    for (int c2 = 0; c2 < 8; ++c2) {
      int col = c2 * 16 + m;
      #pragma unroll
      for (int g = 0; g < 4; ++g) {
        long row = rowb + quad * 4 + g;
        float xh = a2[c2][g];
        xhat[row * 128 + col] = xh;
        float dd = x[row * 128 + col] - xh;
        rsum += C0 - dd * dd * (0.5f / VAR_F);
      }
    }
    #pragma unroll
    for (int off = 1; off < 64; off <<= 1) rsum += __shfl_xor(rsum, off, 64);
    if (lane == 0) atomicAdd(&fbuf[128], rsum);
    __syncthreads();
    if (tid == 0) atomicAdd(&ws[0], fbuf[128]);
  }
}

// ---------------------------------------------------------------------------
// hmm_fused: scan (16 waves = 16 chunks of one batch) + in-LDS combine.
// Last block (ticket ws[5]) writes the final loss.
// ---------------------------------------------------------------------------
__global__ __launch_bounds__(1024) void hmm_fused(
    const float* __restrict__ Q, const float* __restrict__ pi,
    const float* __restrict__ z, const float* __restrict__ init_mean,
    const float* __restrict__ evT, float* __restrict__ xhat,
    float* __restrict__ ws) {
  __shared__ float sP[16][64];
  __shared__ float sacc[16];
  int tid = threadIdx.x;
  int c = tid >> 6, lane = tid & 63;
  int b = blockIdx.x;
  int i = lane >> 3, j = lane & 7;

  float qp[8];
  #pragma unroll
  for (int p = 0; p < 8; ++p) {
    float mr = Q[p * 8 + 0];
    #pragma unroll
    for (int cc = 1; cc < 8; ++cc) mr = fmaxf(mr, Q[p * 8 + cc]);
    float rs = 0.f;
    #pragma unroll
    for (int cc = 0; cc < 8; ++cc) rs += __expf(Q[p * 8 + cc] - mr);
    qp[p] = __expf(Q[p * 8 + i] - mr) / rs;
  }
  float qself;
  {
    float mr = Q[j * 8 + 0];
    #pragma unroll
    for (int cc = 1; cc < 8; ++cc) mr = fmaxf(mr, Q[j * 8 + cc]);
    float rs = 0.f;
    #pragma unroll
    for (int cc = 0; cc < 8; ++cc) rs += __expf(Q[j * 8 + cc] - mr);
    qself = __expf(Q[j * 8 + i] - mr) / rs;
  }

  int t0 = 1 + c * 32;
  int L = (c == 15) ? 31 : 32;
  const float* evI = evT + (long)b * 4096 + (long)i * 512 + t0;

  float f[32];
  float accm = 0.f;
  #pragma unroll
  for (int s = 0; s < 32; ++s) {
    float e = (s < L) ? evI[s] : 0.f;
    float m = e;
    m = fmaxf(m, __shfl_xor(m, 8, 64));
    m = fmaxf(m, __shfl_xor(m, 16, 64));
    m = fmaxf(m, __shfl_xor(m, 32, 64));
    f[s] = __expf(e - m);
    if (s < L) accm += m;
  }

  float P = f[0] * qself;
  #pragma unroll
  for (int s = 1; s < 32; ++s) {
    if (s < L) {
      float a0 = __shfl(P, j,      64);
      float a1 = __shfl(P, 8 + j,  64);
      float a2 = __shfl(P, 16 + j, 64);
      float a3 = __shfl(P, 24 + j, 64);
      float a4 = __shfl(P, 32 + j, 64);
      float a5 = __shfl(P, 40 + j, 64);
      float a6 = __shfl(P, 48 + j, 64);
      float a7 = __shfl(P, 56 + j, 64);
      float sv = ((qp[0] * a0 + qp[1] * a1) + (qp[2] * a2 + qp[3] * a3))
               + ((qp[4] * a4 + qp[5] * a5) + (qp[6] * a6 + qp[7] * a7));
      P = f[s] * sv;
    }
    if ((s & 7) == 7) {
      float mx = P;
      mx = fmaxf(mx, __shfl_xor(mx, 1, 64));
      mx = fmaxf(mx, __shfl_xor(mx, 2, 64));
      mx = fmaxf(mx, __shfl_xor(mx, 4, 64));
      mx = fmaxf(mx, __shfl_xor(mx, 8, 64));
      mx = fmaxf(mx, __shfl_xor(mx, 16, 64));
      mx = fmaxf(mx, __shfl_xor(mx, 32, 64));
      mx = fmaxf(mx, 1e-30f);
      P = P / mx;
      accm += __logf(mx);
    }
  }
  sP[c][lane] = P;
  if (lane == 0) sacc[c] = accm;
  __syncthreads();

  if (c == 0) {
    float mp = pi[0];
    #pragma unroll
    for (int cc = 1; cc < 8; ++cc) mp = fmaxf(mp, pi[cc]);
    float sp = 0.f;
    #pragma unroll
    for (int cc = 0; cc < 8; ++cc) sp += __expf(pi[cc] - mp);
    float lpi = pi[j] - mp - __logf(sp);

    const float* zr = z + (long)b * 8192;
    const float* linv = ws + LINV0_OFF + j * 256;
    float diff[16];
    #pragma unroll
    for (int d = 0; d < 16; ++d) diff[d] = zr[d] - init_mean[j * 16 + d];
    float quad0 = 0.f;
    #pragma unroll
    for (int i2 = 0; i2 < 16; ++i2) {
      float s = 0.f;
      #pragma unroll
      for (int jj = 0; jj < 16; ++jj) s += linv[i2 * 16 + jj] * diff[jj];
      quad0 += s * s;
    }
    float ev0 = -0.5f * (16.f * LOG2PI_F + ws[LOGDET0_OFF + j] + quad0);

    float lp0 = ev0 + lpi;
    float m0 = lp0;
    m0 = fmaxf(m0, __shfl_xor(m0, 1, 64));
    m0 = fmaxf(m0, __shfl_xor(m0, 2, 64));
    m0 = fmaxf(m0, __shfl_xor(m0, 4, 64));
    float u = __expf(lp0 - m0);
    double acc = (double)m0;

    #pragma unroll
    for (int cc2 = 0; cc2 < 16; ++cc2) {
      float Pc = sP[cc2][lane];
      float contrib = Pc * u;
      contrib += __shfl_xor(contrib, 1, 64);
      contrib += __shfl_xor(contrib, 2, 64);
      contrib += __shfl_xor(contrib, 4, 64);
      u = __shfl(contrib, j * 9, 64);
      float mxu = u;
      mxu = fmaxf(mxu, __shfl_xor(mxu, 1, 64));
      mxu = fmaxf(mxu, __shfl_xor(mxu, 2, 64));
      mxu = fmaxf(mxu, __shfl_xor(mxu, 4, 64));
      mxu = fmaxf(mxu, 1e-30f);
      u = u / mxu;
      acc += (double)(__logf(mxu) + sacc[cc2]);
    }
    float su = u;
    su += __shfl_xor(su, 1, 64);
    su += __shfl_xor(su, 2, 64);
    su += __shfl_xor(su, 4, 64);
    float logZ = (float)(acc + (double)__logf(su));
    if (lane == 0) {
      atomicAdd(&ws[2], logZ);
      __threadfence();
      unsigned int t = atomicAdd((unsigned int*)(ws + 5), 1u);
      if (t == gridDim.x - 1) {
        __threadfence();
        float msm = atomicAdd(&ws[2], 0.f);   // coherent read after all adds
        float loss = -((ws[0] - ws[1] + msm) * (1.f / 64.f));
        xhat[LOSS_OFF] = loss;
      }
    }
  }
}

extern "C" void kernel_launch(void* const* d_in, const int* in_sizes, int n_in,
                              void* d_out, int out_size, void* d_ws, size_t ws_size,
                              hipStream_t stream) {
  (void)in_sizes; (void)n_in; (void)out_size; (void)ws_size;
  const float* x   = (const float*)d_in[0];
  const float* eps = (const float*)d_in[1];
  const float* W1  = (const float*)d_in[2];
  const float* b1  = (const float*)d_in[3];
  const float* W2  = (const float*)d_in[4];
  const float* b2  = (const float*)d_in[5];
  const float* Wt1 = (const float*)d_in[6];
  const float* bt1 = (const float*)d_in[7];
  const float* Wt2 = (const float*)d_in[8];
  const float* bt2 = (const float*)d_in[9];
  const float* Wd1 = (const float*)d_in[10];
  const float* bd1 = (const float*)d_in[11];
  const float* Wd2 = (const float*)d_in[12];
  const float* bd2 = (const float*)d_in[13];
  const float* Q   = (const float*)d_in[14];
  const float* pi  = (const float*)d_in[15];
  const float* im  = (const float*)d_in[16];
  const float* ic  = (const float*)d_in[17];
  const float* cv  = (const float*)d_in[18];
  float* out = (float*)d_out;
  float* ws  = (float*)d_ws;
  float* z_out = out + Z_OUT_OFF;
  float* evT  = ws + EVT_WS_OFF;   // in ws so dec can overlap evt
  float* w2l  = out + PBUF_OFF;    // W2L f32 staging (prep -> wcvt)
  unsigned short* wimg = (unsigned short*)(ws + WIMG_F_OFF);

  prep_kernel<<<16, 256, 0, stream>>>(ic, cv, Wt2, bt2, ws, w2l);
  wcvt_kernel<<<144, 256, 0, stream>>>(Wt1, bt1, W1, W2, Wd1, bd1, Wd2, ws, w2l, wimg);
  enc_kernel<<<512, 256, 0, stream>>>(x, eps, b1, b2, wimg, z_out, ws);
  evtdec_kernel<<<dim3(320, 8), 256, 0, stream>>>(x, z_out, bd2, wimg, evT, out, ws);
  hmm_fused<<<64, 1024, 0, stream>>>(Q, pi, z_out, im, evT, out, ws);
}

// Round 10
// 214.840 us; speedup vs baseline: 1.0565x; 1.0565x over previous
//
#include <hip/hip_runtime.h>
#include <math.h>

#define B_SZ   64
#define T_SZ   512
#define DOBS   128
#define DLAT   16
#define DHID   256
#define K_SZ   8
#define ROWS_A 32768   // B*T

#define LOG2PI_F 1.8378770664093453f
#define VAR_F    5.0e-4f

// ws float offsets
#define LINV0_OFF   16
#define LOGDET0_OFF 2064
#define LINVT_OFF   2080
#define LOGDETT_OFF 4128
#define CVEC_OFF    4224      // 8*16 floats: Linv_k @ bt2_k
// ws[0]=recon_sum ws[1]=logq_sum ws[2]=msm_sum ws[5]=hmm ticket
#define WIMG_F_OFF  8192      // bf16 weight images start here (ushort region)
#define EVT_WS_OFF  131072    // evT staging: 262144 floats in ws

// bf16 weight image offsets (in shorts, within wimg)
#define EVT_W1   0            // [k][ch=256][d pad24]  d<16: Wt1, d==16: bt1, d>16: 0
#define EVT_W2   49152        // [k][d2=16][kk pad264] <- (Wt2@LinvT)[k][ch][d2], kk=perm(ch)
#define EVT_LINV 82944        // [k][i=16][j pad24]    <- LinvT[k][i][j]
#define ENC_W1   86016        // [n=256][kk=128 pad136] <- W1[kk][n]
#define ENC_W2   120832       // [n=32][kk=256 pad264]  <- W2[kk][n], kk=perm
#define DEC_W1   129280       // [n=256][d pad24]  d<16: Wd1, d==16: bd1, d>16: 0
#define DEC_W2   135424       // [n=128][kk=256 pad264] <- Wd2[kk][n], kk=perm
#define IND_TOTAL 131072      // prep-independent conversion elements

#define Z_OUT_OFF   4194304   // B*T*DOBS
#define LOSS_OFF    4718592   // + B*T*DLAT

typedef __attribute__((ext_vector_type(8))) short short8;
typedef __attribute__((ext_vector_type(8))) unsigned short ush8;
typedef __attribute__((ext_vector_type(4))) float floatx4;

__device__ __forceinline__ float leakyf(float v) { return v > 0.f ? v : 0.01f * v; }
__device__ __forceinline__ unsigned short f2bf(float f) {
  union { float f; unsigned int u; } v; v.f = f;
  unsigned int lsb = (v.u >> 16) & 1;
  v.u += 0x7fffu + lsb;   // round-to-nearest-even
  return (unsigned short)(v.u >> 16);
}
// packed f32x2 -> bf16x2 (RNE), single VALU op on gfx950
__device__ __forceinline__ unsigned int cvt_pk_bf16(float lo, float hi) {
  unsigned int r;
  asm("v_cvt_pk_bf16_f32 %0, %1, %2" : "=v"(r) : "v"(lo), "v"(hi));
  return r;
}
// softplus via native ocml intrinsics (no denorm guards). |v| <~ 4 here.
__device__ __forceinline__ float softplus_fast(float v) {
  return __logf(1.f + __expf(v));
}
// kk-permutation pairing even/odd channels for b32 ttile writes
__device__ __forceinline__ int permk(int kk) {
  return (kk & ~31) | ((kk & 15) << 1) | ((kk >> 4) & 1);
}

// ---------------------------------------------------------------------------
// prepwcvt: merged prep + weight conversion (one launch, no cross-block deps).
//  blocks 0..15 : Cholesky/Linv/logdet; jobs 8..15 write EVT_W2 + EVT_LINV
//                 bf16 images DIRECTLY (same-block; kills w2l f32 staging)
//  blocks 16..159: grid-stride over prep-INDEPENDENT image conversions.
// ---------------------------------------------------------------------------
__global__ __launch_bounds__(256) void prepwcvt_kernel(
    const float* __restrict__ init_cov, const float* __restrict__ covs,
    const float* __restrict__ Wt1, const float* __restrict__ bt1,
    const float* __restrict__ Wt2, const float* __restrict__ bt2,
    const float* __restrict__ W1, const float* __restrict__ W2,
    const float* __restrict__ Wd1, const float* __restrict__ bd1,
    const float* __restrict__ Wd2,
    float* __restrict__ ws, unsigned short* __restrict__ wimg) {
  int tid = threadIdx.x;
  int bid = blockIdx.x;
  if (bid < 16) {
    __shared__ float M[16][16];
    __shared__ float L[16][16];
    __shared__ float X[16][17];
    int job = bid;
    const float* C = (job < 8) ? (init_cov + job * 256) : (covs + (job - 8) * 256);
    float* logdet = ws + ((job < 8) ? (LOGDET0_OFF + job) : (LOGDETT_OFF + (job - 8)));
    if (job == 0 && tid < 8) ws[tid] = 0.f;
    int i = tid >> 4, j = tid & 15;
    {
      float s = (i == j) ? 1e-6f : 0.f;
      #pragma unroll
      for (int p = 0; p < 16; ++p) s += C[i * 16 + p] * C[j * 16 + p];
      M[i][j] = s;
    }
    __syncthreads();
    for (int c = 0; c < 16; ++c) {
      if (tid == 0) {
        float s = M[c][c];
        for (int p = 0; p < c; ++p) s -= L[c][p] * L[c][p];
        L[c][c] = sqrtf(s);
      }
      __syncthreads();
      if (tid > c && tid < 16) {
        float s = M[tid][c];
        for (int p = 0; p < c; ++p) s -= L[tid][p] * L[c][p];
        L[tid][c] = s / L[c][c];
      }
      __syncthreads();
    }
    if (tid < 16) {
      for (int r = 0; r < 16; ++r) {
        float s = (r == tid) ? 1.f : 0.f;
        for (int p = tid; p < r; ++p) s -= L[r][p] * X[p][tid];
        X[r][tid] = (r >= tid) ? s / L[r][r] : 0.f;
      }
    }
    __syncthreads();
    if (tid == 0) {
      float s = 0.f;
      for (int d = 0; d < 16; ++d) s += logf(L[d][d]);
      *logdet = 2.f * s;
    }
    if (job < 8) {
      ws[LINV0_OFF + job * 256 + i * 16 + j] = X[i][j];   // f32 for ev0
    } else {
      int k = job - 8;
      wimg[EVT_LINV + k * 384 + i * 24 + j] = f2bf(X[i][j]);
      // W2L = Wt2@LinvT -> EVT_W2 bf16 image directly (ch = tid)
      const float* wrow = Wt2 + (long)k * 4096 + tid * 16;
      int pk = permk(tid);
      #pragma unroll
      for (int i2 = 0; i2 < 16; ++i2) {
        float s = 0.f;
        for (int jj = 0; jj <= i2; ++jj) s += wrow[jj] * X[i2][jj];
        wimg[EVT_W2 + k * 4224 + i2 * 264 + pk] = f2bf(s);
      }
      if (tid < 16) {
        float s = 0.f;
        const float* bb = bt2 + k * 16;
        for (int jj = 0; jj <= tid; ++jj) s += bb[jj] * X[tid][jj];
        ws[CVEC_OFF + k * 16 + tid] = s;
      }
    }
  } else {
    for (int e = (bid - 16) * 256 + tid; e < IND_TOTAL; e += 144 * 256) {
      if (e < 65536) {                       // EVT_W1 + bias row (d=16) + zeros
        int k = e >> 13, r = e & 8191, ch = r >> 5, d = r & 31;
        if (d < 24) {
          float v = (d < 16) ? Wt1[k * 4096 + d * 256 + ch]
                             : ((d == 16) ? bt1[k * 256 + ch] : 0.f);
          wimg[EVT_W1 + k * 6144 + ch * 24 + d] = f2bf(v);
        }
      } else if (e < 98304) {                // ENC_W1
        int e2 = e - 65536; int n = e2 >> 7, kk = e2 & 127;
        wimg[ENC_W1 + n * 136 + kk] = f2bf(W1[kk * 256 + n]);
      } else if (e < 106496) {               // ENC_W2, kk permuted
        int e2 = e - 98304; int n = e2 >> 8, kk = e2 & 255;
        wimg[ENC_W2 + n * 264 + permk(kk)] = f2bf(W2[kk * 32 + n]);
      } else if (e < 114688) {               // DEC_W1 + bias row
        int e2 = e - 106496; int n = e2 >> 5, d = e2 & 31;
        if (d < 24) {
          float v = (d < 16) ? Wd1[d * 256 + n] : ((d == 16) ? bd1[n] : 0.f);
          wimg[DEC_W1 + n * 24 + d] = f2bf(v);
        }
      } else {                               // DEC_W2, kk permuted
        int e2 = e - 114688; int kk = e2 >> 7, n = e2 & 127;
        wimg[DEC_W2 + n * 264 + permk(kk)] = f2bf(Wd2[kk * 128 + n]);
      }
    }
  }
}

// ---------------------------------------------------------------------------
// encoder (bf16 MFMA, interleaved): per 16-row tile,
// GEMM1 col-pair -> leaky -> paired b32 LDS transpose tile -> GEMM2.
// ---------------------------------------------------------------------------
__global__ __launch_bounds__(256) void enc_kernel(
    const float* __restrict__ x, const float* __restrict__ eps,
    const float* __restrict__ b1, const float* __restrict__ b2,
    const unsigned short* __restrict__ wimg,
    float* __restrict__ z_out, float* __restrict__ ws) {
  __shared__ __align__(16) unsigned short w2t[32 * 264];
  __shared__ __align__(16) unsigned short ttile[4][16 * 56];
  __shared__ float b1s[256];
  __shared__ float sred;
  int tid = threadIdx.x;
  if (tid == 0) sred = 0.f;
  {
    const ush8* s2 = (const ush8*)(wimg + ENC_W2);
    for (int e = tid; e < 1056; e += 256) ((ush8*)w2t)[e] = s2[e];
    b1s[tid] = b1[tid];
  }
  __syncthreads();

  int wid = tid >> 6, lane = tid & 63;
  int m = lane & 15, quad = lane >> 4;
  unsigned short* tt = ttile[wid];
  const unsigned short* w1i = wimg + ENC_W1;
  long rowb = (long)blockIdx.x * 64 + wid * 16;

  short8 xa[4];
  const float* xp = x + (rowb + m) * 128 + quad * 8;
  #pragma unroll
  for (int kt = 0; kt < 4; ++kt) {
    float4 f0 = *(const float4*)(xp + kt * 32);
    float4 f1 = *(const float4*)(xp + kt * 32 + 4);
    union { unsigned int u[4]; short8 s; } cv;
    cv.u[0] = cvt_pk_bf16(f0.x, f0.y);
    cv.u[1] = cvt_pk_bf16(f0.z, f0.w);
    cv.u[2] = cvt_pk_bf16(f1.x, f1.y);
    cv.u[3] = cvt_pk_bf16(f1.z, f1.w);
    xa[kt] = cv.s;
  }
  float bm0 = b2[m], bm1 = b2[16 + m];
  floatx4 a20 = {bm0, bm0, bm0, bm0};
  floatx4 a21 = {bm1, bm1, bm1, bm1};
  #pragma unroll
  for (int cp = 0; cp < 8; ++cp) {
    floatx4 a1h[2];
    #pragma unroll
    for (int h = 0; h < 2; ++h) {
      int c = cp * 2 + h;
      float bias = b1s[c * 16 + m];
      floatx4 a1 = {bias, bias, bias, bias};
      #pragma unroll
      for (int kt = 0; kt < 4; ++kt) {
        short8 bf = *(const short8*)&w1i[(c * 16 + m) * 136 + kt * 32 + quad * 8];
        a1 = __builtin_amdgcn_mfma_f32_16x16x32_bf16(xa[kt], bf, a1, 0, 0, 0);
      }
      a1h[h] = a1;
    }
    #pragma unroll
    for (int g = 0; g < 4; ++g) {
      unsigned int p = cvt_pk_bf16(leakyf(a1h[0][g]), leakyf(a1h[1][g]));
      *(unsigned int*)&tt[(quad * 4 + g) * 56 + 2 * m] = p;
    }
    short8 ha = *(const short8*)&tt[m * 56 + quad * 8];
    short8 wb0 = *(const short8*)&w2t[m * 264 + cp * 32 + quad * 8];
    short8 wb1 = *(const short8*)&w2t[(16 + m) * 264 + cp * 32 + quad * 8];
    a20 = __builtin_amdgcn_mfma_f32_16x16x32_bf16(ha, wb0, a20, 0, 0, 0);
    a21 = __builtin_amdgcn_mfma_f32_16x16x32_bf16(ha, wb1, a21, 0, 0, 0);
  }
  // epilogue: z + logq
  float logq_acc = 0.f;
  #pragma unroll
  for (int g = 0; g < 4; ++g) {
    long row = rowb + quad * 4 + g;
    float mu = a20[g], lv = a21[g];
    float ev = eps[row * 16 + m];
    float zv = mu + __expf(0.5f * lv) * ev;
    z_out[row * 16 + m] = zv;
    float zz = zv - mu;
    logq_acc += lv + zz * zz * __expf(-lv);
  }
  #pragma unroll
  for (int off = 1; off < 64; off <<= 1) logq_acc += __shfl_xor(logq_acc, off, 64);
  if (lane == 0) atomicAdd(&sred, -0.5f * logq_acc);
  __syncthreads();
  if (tid == 0) atomicAdd(&ws[1], sred - 0.5f * 16.f * LOG2PI_F * 64.f);
}

// ---------------------------------------------------------------------------
// evtdec (r5 structure): blockIdx.x<256 -> evt tile (k=blockIdx.y);
// blockIdx.x>=256 -> dec (decb = by*64 + bx-256), W1 LDS-staged.
// ---------------------------------------------------------------------------
__global__ __launch_bounds__(256, 6) void evtdec_kernel(
    const float* __restrict__ x, const float* __restrict__ z,
    const float* __restrict__ bd2,
    const unsigned short* __restrict__ wimg,
    float* __restrict__ evT, float* __restrict__ xhat,
    float* __restrict__ ws) {
  __shared__ __align__(16) unsigned short wbuf[6144];     // evt: w2t(4224)+linvb(384) | dec: w1t(6144)
  __shared__ __align__(16) unsigned short ttile[4][16 * 56];
  __shared__ float fbuf[132];                              // dec: bd2s[128], fbuf[128]=sred
  int tid = threadIdx.x;
  int wid = tid >> 6, lane = tid & 63;
  int m = lane & 15, quad = lane >> 4;
  unsigned short* tt = ttile[wid];

  if (blockIdx.x < 256) {
    // ================= evt path =================
    int k = blockIdx.y;
    {
      const ush8* s2 = (const ush8*)(wimg + EVT_W2 + k * 4224);
      for (int e = tid; e < 528; e += 256) ((ush8*)wbuf)[e] = s2[e];
      if (tid < 48) ((ush8*)(wbuf + 4224))[tid] = ((const ush8*)(wimg + EVT_LINV + k * 384))[tid];
    }
    float logdetk = ws[LOGDETT_OFF + k];
    __syncthreads();
    const unsigned short* w2t = wbuf;
    const unsigned short* linvb = wbuf + 4224;
    const unsigned short* w1i = wimg + EVT_W1 + k * 6144;
    float cval = ws[CVEC_OFF + k * 16 + m];

    for (int tile = 0; tile < 2; ++tile) {
      long rowb = (long)blockIdx.x * 128 + wid * 32 + tile * 16;
      short8 za = (short8)0;
      if (quad < 2) {
        const float* zp = z + (rowb + m) * 16 + quad * 8;
        float4 f0 = *(const float4*)zp;
        float4 f1 = *(const float4*)(zp + 4);
        union { unsigned int u[4]; short8 s; } cv;
        cv.u[0] = cvt_pk_bf16(f0.x, f0.y);
        cv.u[1] = cvt_pk_bf16(f0.z, f0.w);
        cv.u[2] = cvt_pk_bf16(f1.x, f1.y);
        cv.u[3] = cvt_pk_bf16(f1.z, f1.w);
        za = cv.s;
      } else if (quad == 2) {
        za[0] = (short)0x3F80;   // bf16(1.0) -> picks up bias row d=16
      }
      short8 za2 = (short8)0;
      if (quad < 2) {
        long r2 = rowb + m + 1; if (r2 > 32767) r2 = 32767;
        const float* zp2 = z + r2 * 16 + quad * 8;
        float4 f0 = *(const float4*)zp2;
        float4 f1 = *(const float4*)(zp2 + 4);
        union { unsigned int u[4]; short8 s; } cv;
        cv.u[0] = cvt_pk_bf16(f0.x, f0.y);
        cv.u[1] = cvt_pk_bf16(f0.z, f0.w);
        cv.u[2] = cvt_pk_bf16(f1.x, f1.y);
        cv.u[3] = cvt_pk_bf16(f1.z, f1.w);
        za2 = cv.s;
      }
      floatx4 a2 = {cval, cval, cval, cval};   // cvec + ht@W2L accumulates here
      #pragma unroll
      for (int cp = 0; cp < 8; ++cp) {
        floatx4 a1h[2];
        #pragma unroll
        for (int h = 0; h < 2; ++h) {
          int c = cp * 2 + h;
          short8 bfrag = (short8)0;
          if (quad < 3) bfrag = *(const short8*)&w1i[(c * 16 + m) * 24 + quad * 8];
          floatx4 a1 = {0.f, 0.f, 0.f, 0.f};
          a1 = __builtin_amdgcn_mfma_f32_16x16x32_bf16(za, bfrag, a1, 0, 0, 0);
          a1h[h] = a1;
        }
        #pragma unroll
        for (int g = 0; g < 4; ++g) {
          unsigned int p = cvt_pk_bf16(softplus_fast(a1h[0][g]), softplus_fast(a1h[1][g]));
          *(unsigned int*)&tt[(quad * 4 + g) * 56 + 2 * m] = p;
        }
        short8 ha = *(const short8*)&tt[m * 56 + quad * 8];
        short8 wb = *(const short8*)&w2t[m * 264 + cp * 32 + quad * 8];
        a2 = __builtin_amdgcn_mfma_f32_16x16x32_bf16(ha, wb, a2, 0, 0, 0);
      }
      short8 lb = (short8)0;
      if (quad < 2) lb = *(const short8*)&linvb[m * 24 + quad * 8];
      floatx4 a3 = {0.f, 0.f, 0.f, 0.f};
      a3 = __builtin_amdgcn_mfma_f32_16x16x32_bf16(za2, lb, a3, 0, 0, 0);
      #pragma unroll
      for (int g = 0; g < 4; ++g) {
        float v = a3[g] - a2[g];
        v = v * v;
        v += __shfl_xor(v, 1, 64);
        v += __shfl_xor(v, 2, 64);
        v += __shfl_xor(v, 4, 64);
        v += __shfl_xor(v, 8, 64);
        long grow = rowb + quad * 4 + g;
        if (m == 0 && (grow & 511) != 511) {
          long r1 = grow + 1;
          evT[(r1 >> 9) * 4096 + (long)k * 512 + (r1 & 511)] =
              -0.5f * (16.f * LOG2PI_F + logdetk + v);
        }
      }
    }
  } else {
    // ================= dec path =================
    int decb = blockIdx.y * 64 + ((int)blockIdx.x - 256);
    if (tid == 0) fbuf[128] = 0.f;
    {
      const ush8* s1 = (const ush8*)(wimg + DEC_W1);
      for (int e = tid; e < 768; e += 256) ((ush8*)wbuf)[e] = s1[e];
      if (tid < 128) fbuf[tid] = bd2[tid];
    }
    __syncthreads();
    const unsigned short* w1t = wbuf;
    const unsigned short* w2i = wimg + DEC_W2;
    long rowb = (long)decb * 64 + wid * 16;

    short8 za = (short8)0;
    if (quad < 2) {
      const float* zp = z + (rowb + m) * 16 + quad * 8;
      float4 f0 = *(const float4*)zp;
      float4 f1 = *(const float4*)(zp + 4);
      union { unsigned int u[4]; short8 s; } cv;
      cv.u[0] = cvt_pk_bf16(f0.x, f0.y);
      cv.u[1] = cvt_pk_bf16(f0.z, f0.w);
      cv.u[2] = cvt_pk_bf16(f1.x, f1.y);
      cv.u[3] = cvt_pk_bf16(f1.z, f1.w);
      za = cv.s;
    } else if (quad == 2) {
      za[0] = (short)0x3F80;   // bias row pickup
    }
    floatx4 a2[8];
    #pragma unroll
    for (int c2 = 0; c2 < 8; ++c2) {
      float bv = fbuf[c2 * 16 + m];
      a2[c2] = (floatx4){bv, bv, bv, bv};
    }
    #pragma unroll
    for (int cp = 0; cp < 8; ++cp) {
      floatx4 a1h[2];
      #pragma unroll
      for (int h = 0; h < 2; ++h) {
        int c = cp * 2 + h;
        short8 bfrag = (short8)0;
        if (quad < 3) bfrag = *(const short8*)&w1t[(c * 16 + m) * 24 + quad * 8];
        floatx4 a1 = {0.f, 0.f, 0.f, 0.f};
        a1 = __builtin_amdgcn_mfma_f32_16x16x32_bf16(za, bfrag, a1, 0, 0, 0);
        a1h[h] = a1;
      }
      #pragma unroll
      for (int g = 0; g < 4; ++g) {
        unsigned int p = cvt_pk_bf16(leakyf(a1h[0][g]), leakyf(a1h[1][g]));
        *(unsigned int*)&tt[(quad * 4 + g) * 56 + 2 * m] = p;
      }
      short8 ha = *(const short8*)&tt[m * 56 + quad * 8];
      #pragma unroll
      for (int c2 = 0; c2 < 8; ++c2) {
        short8 wb = *(const short8*)&w2i[(c2 * 16 + m) * 264 + cp * 32 + quad * 8];
        a2[c2] = __builtin_amdgcn_mfma_f32_16x16x32_bf16(ha, wb, a2[c2], 0, 0, 0);
      }
    }
    const float C0 = -0.5f * logf(6.2831853071795864f * VAR_F);
    float rsum = 0.f;
    #pragma unroll
    for (int c2 = 0; c2 < 8; ++c2) {
      int col = c2 * 16 + m;
      #pragma unroll
      for (int g = 0; g < 4; ++g) {
        long row = rowb + quad * 4 + g;
        float xh = a2[c2][g];
        xhat[row * 128 + col] = xh;
        float dd = x[row * 128 + col] - xh;
        rsum += C0 - dd * dd * (0.5f / VAR_F);
      }
    }
    #pragma unroll
    for (int off = 1; off < 64; off <<= 1) rsum += __shfl_xor(rsum, off, 64);
    if (lane == 0) atomicAdd(&fbuf[128], rsum);
    __syncthreads();
    if (tid == 0) atomicAdd(&ws[0], fbuf[128]);
  }
}

// ---------------------------------------------------------------------------
// hmm_fused: scan (16 waves = 16 chunks of one batch) + in-LDS combine.
// Last block (ticket ws[5]) writes the final loss.
// ---------------------------------------------------------------------------
__global__ __launch_bounds__(1024) void hmm_fused(
    const float* __restrict__ Q, const float* __restrict__ pi,
    const float* __restrict__ z, const float* __restrict__ init_mean,
    const float* __restrict__ evT, float* __restrict__ xhat,
    float* __restrict__ ws) {
  __shared__ float sP[16][64];
  __shared__ float sacc[16];
  int tid = threadIdx.x;
  int c = tid >> 6, lane = tid & 63;
  int b = blockIdx.x;
  int i = lane >> 3, j = lane & 7;

  float qp[8];
  #pragma unroll
  for (int p = 0; p < 8; ++p) {
    float mr = Q[p * 8 + 0];
    #pragma unroll
    for (int cc = 1; cc < 8; ++cc) mr = fmaxf(mr, Q[p * 8 + cc]);
    float rs = 0.f;
    #pragma unroll
    for (int cc = 0; cc < 8; ++cc) rs += __expf(Q[p * 8 + cc] - mr);
    qp[p] = __expf(Q[p * 8 + i] - mr) / rs;
  }
  float qself;
  {
    float mr = Q[j * 8 + 0];
    #pragma unroll
    for (int cc = 1; cc < 8; ++cc) mr = fmaxf(mr, Q[j * 8 + cc]);
    float rs = 0.f;
    #pragma unroll
    for (int cc = 0; cc < 8; ++cc) rs += __expf(Q[j * 8 + cc] - mr);
    qself = __expf(Q[j * 8 + i] - mr) / rs;
  }

  int t0 = 1 + c * 32;
  int L = (c == 15) ? 31 : 32;
  const float* evI = evT + (long)b * 4096 + (long)i * 512 + t0;

  float f[32];
  float accm = 0.f;
  #pragma unroll
  for (int s = 0; s < 32; ++s) {
    float e = (s < L) ? evI[s] : 0.f;
    float mm = e;
    mm = fmaxf(mm, __shfl_xor(mm, 8, 64));
    mm = fmaxf(mm, __shfl_xor(mm, 16, 64));
    mm = fmaxf(mm, __shfl_xor(mm, 32, 64));
    f[s] = __expf(e - mm);
    if (s < L) accm += mm;
  }

  float P = f[0] * qself;
  #pragma unroll
  for (int s = 1; s < 32; ++s) {
    if (s < L) {
      float a0 = __shfl(P, j,      64);
      float a1 = __shfl(P, 8 + j,  64);
      float a2 = __shfl(P, 16 + j, 64);
      float a3 = __shfl(P, 24 + j, 64);
      float a4 = __shfl(P, 32 + j, 64);
      float a5 = __shfl(P, 40 + j, 64);
      float a6 = __shfl(P, 48 + j, 64);
      float a7 = __shfl(P, 56 + j, 64);
      float sv = ((qp[0] * a0 + qp[1] * a1) + (qp[2] * a2 + qp[3] * a3))
               + ((qp[4] * a4 + qp[5] * a5) + (qp[6] * a6 + qp[7] * a7));
      P = f[s] * sv;
    }
    if ((s & 7) == 7) {
      float mx = P;
      mx = fmaxf(mx, __shfl_xor(mx, 1, 64));
      mx = fmaxf(mx, __shfl_xor(mx, 2, 64));
      mx = fmaxf(mx, __shfl_xor(mx, 4, 64));
      mx = fmaxf(mx, __shfl_xor(mx, 8, 64));
      mx = fmaxf(mx, __shfl_xor(mx, 16, 64));
      mx = fmaxf(mx, __shfl_xor(mx, 32, 64));
      mx = fmaxf(mx, 1e-30f);
      P = P / mx;
      accm += __logf(mx);
    }
  }
  sP[c][lane] = P;
  if (lane == 0) sacc[c] = accm;
  __syncthreads();

  if (c == 0) {
    float mp = pi[0];
    #pragma unroll
    for (int cc = 1; cc < 8; ++cc) mp = fmaxf(mp, pi[cc]);
    float sp = 0.f;
    #pragma unroll
    for (int cc = 0; cc < 8; ++cc) sp += __expf(pi[cc] - mp);
    float lpi = pi[j] - mp - __logf(sp);

    const float* zr = z + (long)b * 8192;
    const float* linv = ws + LINV0_OFF + j * 256;
    float diff[16];
    #pragma unroll
    for (int d = 0; d < 16; ++d) diff[d] = zr[d] - init_mean[j * 16 + d];
    float quad0 = 0.f;
    #pragma unroll
    for (int i2 = 0; i2 < 16; ++i2) {
      float s = 0.f;
      #pragma unroll
      for (int jj = 0; jj < 16; ++jj) s += linv[i2 * 16 + jj] * diff[jj];
      quad0 += s * s;
    }
    float ev0 = -0.5f * (16.f * LOG2PI_F + ws[LOGDET0_OFF + j] + quad0);

    float lp0 = ev0 + lpi;
    float m0 = lp0;
    m0 = fmaxf(m0, __shfl_xor(m0, 1, 64));
    m0 = fmaxf(m0, __shfl_xor(m0, 2, 64));
    m0 = fmaxf(m0, __shfl_xor(m0, 4, 64));
    float u = __expf(lp0 - m0);
    double acc = (double)m0;

    #pragma unroll
    for (int cc2 = 0; cc2 < 16; ++cc2) {
      float Pc = sP[cc2][lane];
      float contrib = Pc * u;
      contrib += __shfl_xor(contrib, 1, 64);
      contrib += __shfl_xor(contrib, 2, 64);
      contrib += __shfl_xor(contrib, 4, 64);
      u = __shfl(contrib, j * 9, 64);
      float mxu = u;
      mxu = fmaxf(mxu, __shfl_xor(mxu, 1, 64));
      mxu = fmaxf(mxu, __shfl_xor(mxu, 2, 64));
      mxu = fmaxf(mxu, __shfl_xor(mxu, 4, 64));
      mxu = fmaxf(mxu, 1e-30f);
      u = u / mxu;
      acc += (double)(__logf(mxu) + sacc[cc2]);
    }
    float su = u;
    su += __shfl_xor(su, 1, 64);
    su += __shfl_xor(su, 2, 64);
    su += __shfl_xor(su, 4, 64);
    float logZ = (float)(acc + (double)__logf(su));
    if (lane == 0) {
      atomicAdd(&ws[2], logZ);
      __threadfence();
      unsigned int t = atomicAdd((unsigned int*)(ws + 5), 1u);
      if (t == gridDim.x - 1) {
        __threadfence();
        float msm = atomicAdd(&ws[2], 0.f);   // coherent read after all adds
        float loss = -((ws[0] - ws[1] + msm) * (1.f / 64.f));
        xhat[LOSS_OFF] = loss;
      }
    }
  }
}

extern "C" void kernel_launch(void* const* d_in, const int* in_sizes, int n_in,
                              void* d_out, int out_size, void* d_ws, size_t ws_size,
                              hipStream_t stream) {
  (void)in_sizes; (void)n_in; (void)out_size; (void)ws_size;
  const float* x   = (const float*)d_in[0];
  const float* eps = (const float*)d_in[1];
  const float* W1  = (const float*)d_in[2];
  const float* b1  = (const float*)d_in[3];
  const float* W2  = (const float*)d_in[4];
  const float* b2  = (const float*)d_in[5];
  const float* Wt1 = (const float*)d_in[6];
  const float* bt1 = (const float*)d_in[7];
  const float* Wt2 = (const float*)d_in[8];
  const float* bt2 = (const float*)d_in[9];
  const float* Wd1 = (const float*)d_in[10];
  const float* bd1 = (const float*)d_in[11];
  const float* Wd2 = (const float*)d_in[12];
  const float* bd2 = (const float*)d_in[13];
  const float* Q   = (const float*)d_in[14];
  const float* pi  = (const float*)d_in[15];
  const float* im  = (const float*)d_in[16];
  const float* ic  = (const float*)d_in[17];
  const float* cv  = (const float*)d_in[18];
  float* out = (float*)d_out;
  float* ws  = (float*)d_ws;
  float* z_out = out + Z_OUT_OFF;
  float* evT  = ws + EVT_WS_OFF;   // in ws so dec can overlap evt
  unsigned short* wimg = (unsigned short*)(ws + WIMG_F_OFF);

  prepwcvt_kernel<<<160, 256, 0, stream>>>(ic, cv, Wt1, bt1, Wt2, bt2,
                                           W1, W2, Wd1, bd1, Wd2, ws, wimg);
  enc_kernel<<<512, 256, 0, stream>>>(x, eps, b1, b2, wimg, z_out, ws);
  evtdec_kernel<<<dim3(320, 8), 256, 0, stream>>>(x, z_out, bd2, wimg, evT, out, ws);
  hmm_fused<<<64, 1024, 0, stream>>>(Q, pi, z_out, im, evT, out, ws);
}